// Round 9
// baseline (413.664 us; speedup 1.0000x reference)
//
#include <hip/hip_runtime.h>
#include <hip/hip_bf16.h>

#define EMBED 1024
#define THREE_EMBED 3072
#define NHEAD 16
#define HDIM 64
#define MTOT 16384
#define LTOT 16383

typedef __attribute__((ext_vector_type(8))) short bf16x8;
typedef __attribute__((ext_vector_type(4))) float f32x4;

__device__ __forceinline__ unsigned short f2b(float f) {
  union { float f; unsigned u; } v; v.f = f;
  unsigned r = v.u + 0x7fffu + ((v.u >> 16) & 1u);
  return (unsigned short)(r >> 16);
}
__device__ __forceinline__ float b2f(unsigned short h) {
  union { unsigned u; float f; } v; v.u = ((unsigned)h) << 16;
  return v.f;
}

__device__ __forceinline__ void gload16(const void* g, void* l) {
  __builtin_amdgcn_global_load_lds(
      (const __attribute__((address_space(1))) void*)g,
      (__attribute__((address_space(3))) void*)l, 16, 0, 0);
}

#define BARRIER() asm volatile("s_barrier" ::: "memory")
#define VMCNT(N) asm volatile("s_waitcnt vmcnt(" #N ")" ::: "memory")
#define LGKM0()  asm volatile("s_waitcnt lgkmcnt(0)" ::: "memory")

// ---------------------------------------------------------------------------
// cast pass: x (+padding) -> xb bf16; qkv_w -> wqb; optional proj_w -> wpb
// (np = proj elements/8, 0 when not fused); inv[kvi[i]] = i.
// ---------------------------------------------------------------------------
__global__ __launch_bounds__(256) void cast_inputs(
    const float* __restrict__ x, const float* __restrict__ padding,
    const float* __restrict__ wq, const float* __restrict__ wp,
    const int* __restrict__ kvi,
    unsigned short* __restrict__ xb, unsigned short* __restrict__ wqb,
    unsigned short* __restrict__ wpb, int* __restrict__ inv, int np)
{
  const int NX = MTOT * EMBED / 8;
  const int NQ = THREE_EMBED * EMBED / 8;
  const int total = NX + NQ + np;
  int g = blockIdx.x * 256 + threadIdx.x;
  const int stride = gridDim.x * 256;
  for (; g < total + MTOT; g += stride) {
    if (g >= total) {
      int i = g - total;
      inv[kvi[i]] = i;
      continue;
    }
    const float* src;
    unsigned short* dst;
    if (g < NX) {
      size_t e = (size_t)g * 8;
      int row = (int)(e >> 10);
      src = (row < LTOT) ? (x + e) : (padding + (e - (size_t)LTOT * 1024));
      dst = xb + e;
    } else if (g < NX + NQ) {
      size_t e = (size_t)(g - NX) * 8;
      src = wq + e;
      dst = wqb + e;
    } else {
      size_t e = (size_t)(g - NX - NQ) * 8;
      src = wp + e;
      dst = wpb + e;
    }
    float4 a = *(const float4*)src;
    float4 b = *(const float4*)(src + 4);
    ushort4 u0, u1;
    u0.x = f2b(a.x); u0.y = f2b(a.y); u0.z = f2b(a.z); u0.w = f2b(a.w);
    u1.x = f2b(b.x); u1.y = f2b(b.y); u1.z = f2b(b.z); u1.w = f2b(b.w);
    *(ushort4*)dst = u0;
    *(ushort4*)(dst + 4) = u1;
  }
}

// ---------------------------------------------------------------------------
// 256x256 8-phase GEMM (T2+T3+T4+T5), C = A @ B^T + bias. (unchanged r7)
// ---------------------------------------------------------------------------
template <int EPI>
__global__ __launch_bounds__(512, 2) void gemm256(
    const unsigned short* __restrict__ A, const unsigned short* __restrict__ B,
    const float* __restrict__ bias, const int* __restrict__ idx,
    unsigned short* __restrict__ outb, float* __restrict__ outf)
{
  __shared__ __align__(16) unsigned short lds[65536];  // 128 KiB
  const int t = threadIdx.x;
  const int lane = t & 63, wid = t >> 6;
  const int l15 = lane & 15, quad = lane >> 4;
  const int wr = wid >> 2, wc = wid & 3;
  const int bm = blockIdx.x, bn = blockIdx.y;

  const int srow = wid * 8 + (lane >> 3);
  const int scol = ((lane & 7) ^ (lane >> 3)) * 8;
  const unsigned short* gA = A + (size_t)(bm * 256 + srow) * EMBED + scol;
  const unsigned short* gB = B + (size_t)(bn * 256 + srow) * EMBED + scol;

  auto stA = [&](int p, int R0, int kt) {
    const unsigned short* g = gA + (size_t)R0 * EMBED + kt * 64;
    char* d = (char*)lds + p * 32768 + R0 * 128 + wid * 1024;
    gload16(g, d);
    gload16(g + (size_t)64 * EMBED, d + 8192);
  };
  auto stB = [&](int p, int R0, int kt) {
    const unsigned short* g = gB + (size_t)R0 * EMBED + kt * 64;
    char* d = (char*)lds + 65536 + p * 32768 + R0 * 128 + wid * 1024;
    gload16(g, d);
    gload16(g + (size_t)64 * EMBED, d + 8192);
  };

  const int aOff = (wr * 128 + l15) * 64;
  const int bOff = (wc * 64 + l15) * 64;
  const int swz0 = (quad ^ (l15 & 7)) * 8;
  const int swz1 = ((quad + 4) ^ (l15 & 7)) * 8;

  f32x4 acc[8][4];
#pragma unroll
  for (int i = 0; i < 8; ++i)
#pragma unroll
    for (int j = 0; j < 4; ++j) acc[i][j] = (f32x4){0.f, 0.f, 0.f, 0.f};

  stA(0, 0, 0); stA(0, 128, 0); stB(0, 0, 0); stB(0, 128, 0);
  stB(1, 0, 1); stB(1, 128, 1);
  asm volatile("s_waitcnt vmcnt(4)" ::: "memory");
  BARRIER();

#define MFMAGRP(MB)                                                          \
  _Pragma("unroll") for (int m = 0; m < 4; ++m)                              \
      _Pragma("unroll") for (int n = 0; n < 4; ++n)                          \
          acc[(MB) + m][n] = __builtin_amdgcn_mfma_f32_16x16x32_bf16(        \
              a[m], b[n], acc[(MB) + m][n], 0, 0, 0);

#define TILE(P, KT, STA, STB, WCNT)                                          \
  {                                                                          \
    const unsigned short* Ab = lds + (P) * 16384 + aOff;                     \
    const unsigned short* Bb = lds + 32768 + (P) * 16384 + bOff;             \
    bf16x8 a[4], b[4];                                                       \
    { /* phase 0: ks0, mt0-3 */                                              \
      _Pragma("unroll") for (int n = 0; n < 4; ++n)                          \
          b[n] = *(const bf16x8*)(Bb + n * 1024 + swz0);                     \
      _Pragma("unroll") for (int m = 0; m < 4; ++m)                          \
          a[m] = *(const bf16x8*)(Ab + m * 1024 + swz0);                     \
      if (STA) stA((P) ^ 1, 0, (KT) + 1);                                    \
      BARRIER();                                                             \
      __builtin_amdgcn_s_setprio(1);                                         \
      MFMAGRP(0);                                                            \
      __builtin_amdgcn_s_setprio(0);                                         \
      BARRIER();                                                             \
    }                                                                        \
    { /* phase 1: ks0, mt4-7 */                                              \
      _Pragma("unroll") for (int m = 0; m < 4; ++m)                          \
          a[m] = *(const bf16x8*)(Ab + (4 + m) * 1024 + swz0);               \
      if (STA) stA((P) ^ 1, 128, (KT) + 1);                                  \
      BARRIER();                                                             \
      __builtin_amdgcn_s_setprio(1);                                         \
      MFMAGRP(4);                                                            \
      __builtin_amdgcn_s_setprio(0);                                         \
      BARRIER();                                                             \
    }                                                                        \
    { /* phase 2: ks1, mt0-3 */                                              \
      _Pragma("unroll") for (int n = 0; n < 4; ++n)                          \
          b[n] = *(const bf16x8*)(Bb + n * 1024 + swz1);                     \
      _Pragma("unroll") for (int m = 0; m < 4; ++m)                          \
          a[m] = *(const bf16x8*)(Ab + m * 1024 + swz1);                     \
      if (STB) stB((P), 0, (KT) + 2);                                        \
      BARRIER();                                                             \
      __builtin_amdgcn_s_setprio(1);                                         \
      MFMAGRP(0);                                                            \
      __builtin_amdgcn_s_setprio(0);                                         \
      BARRIER();                                                             \
    }                                                                        \
    { /* phase 3: ks1, mt4-7 */                                              \
      _Pragma("unroll") for (int m = 0; m < 4; ++m)                          \
          a[m] = *(const bf16x8*)(Ab + (4 + m) * 1024 + swz1);               \
      if (STB) stB((P), 128, (KT) + 2);                                      \
      BARRIER();                                                             \
      __builtin_amdgcn_s_setprio(1);                                         \
      MFMAGRP(4);                                                            \
      __builtin_amdgcn_s_setprio(0);                                         \
      if ((WCNT) == 4) asm volatile("s_waitcnt vmcnt(4)" ::: "memory");      \
      if ((WCNT) == 0) asm volatile("s_waitcnt vmcnt(0)" ::: "memory");      \
      BARRIER();                                                             \
    }                                                                        \
  }

#pragma unroll 1
  for (int t2 = 0; t2 < 7; ++t2) {
    const int kt = t2 * 2;
    TILE(0, kt, 1, 1, 4);
    TILE(1, kt + 1, 1, 1, 4);
  }
  TILE(0, 14, 1, 0, 0);
  TILE(1, 15, 0, 0, -1);
#undef TILE
#undef MFMAGRP

  float bv[4];
#pragma unroll
  for (int nt = 0; nt < 4; ++nt)
    bv[nt] = bias[bn * 256 + wc * 64 + nt * 16 + l15];
  if constexpr (EPI == 0) {
    const int hh = bn * 4 + wc;
    unsigned short* buf = outb + (size_t)hh * (MTOT * HDIM);
#pragma unroll
    for (int mt = 0; mt < 8; ++mt) {
#pragma unroll
      for (int reg = 0; reg < 4; ++reg) {
        int row = bm * 256 + wr * 128 + mt * 16 + quad * 4 + reg;
        int i = idx[row];  // inv[]
#pragma unroll
        for (int nt = 0; nt < 4; ++nt)
          buf[(size_t)i * HDIM + nt * 16 + l15] =
              f2b(acc[mt][nt][reg] + bv[nt]);
      }
    }
  } else {
    const int col = bn * 256 + wc * 64;
#pragma unroll
    for (int mt = 0; mt < 8; ++mt) {
#pragma unroll
      for (int reg = 0; reg < 4; ++reg) {
        int i = bm * 256 + wr * 128 + mt * 16 + quad * 4 + reg;
        int orow = idx[i];  // kvi[]
        if (orow < LTOT) {
#pragma unroll
          for (int nt = 0; nt < 4; ++nt)
            outf[(size_t)orow * EMBED + col + nt * 16 + l15] =
                acc[mt][nt][reg] + bv[nt];
        }
      }
    }
  }
}

// ---------------------------------------------------------------------------
// rope_qk: in-place RoPE on qkvh head-slots 0..31 (Q scaled by 0.125).
// ---------------------------------------------------------------------------
__global__ __launch_bounds__(256) void rope_qk(
    const float* __restrict__ rope_cos, const float* __restrict__ rope_sin,
    unsigned short* __restrict__ qkvh)
{
  int g = blockIdx.x * 256 + threadIdx.x;
  int dc = g & 3;
  int i  = (g >> 2) & (MTOT - 1);
  int hh = g >> 16;
  unsigned short* p = qkvh + ((size_t)hh * MTOT + i) * HDIM;
  bf16x8 lo = *(const bf16x8*)(p + dc * 8);
  bf16x8 hi = *(const bf16x8*)(p + 32 + dc * 8);
  const float* cp = rope_cos + (size_t)i * HDIM + dc * 8;
  const float* sp = rope_sin + (size_t)i * HDIM + dc * 8;
  float cl[8], ch[8], sl[8], sh[8];
  *(float4*)(cl)     = *(const float4*)(cp);
  *(float4*)(cl + 4) = *(const float4*)(cp + 4);
  *(float4*)(ch)     = *(const float4*)(cp + 32);
  *(float4*)(ch + 4) = *(const float4*)(cp + 36);
  *(float4*)(sl)     = *(const float4*)(sp);
  *(float4*)(sl + 4) = *(const float4*)(sp + 4);
  *(float4*)(sh)     = *(const float4*)(sp + 32);
  *(float4*)(sh + 4) = *(const float4*)(sp + 36);
  const float sc = (hh < 16) ? 0.125f : 1.0f;
  bf16x8 olo, ohi;
#pragma unroll
  for (int j = 0; j < 8; ++j) {
    float a = b2f((unsigned short)lo[j]);
    float b = b2f((unsigned short)hi[j]);
    olo[j] = (short)f2b((a * cl[j] - b * sl[j]) * sc);
    ohi[j] = (short)f2b((b * ch[j] + a * sh[j]) * sc);
  }
  *(bf16x8*)(p + dc * 8) = olo;
  *(bf16x8*)(p + 32 + dc * 8) = ohi;
}

// ---------------------------------------------------------------------------
// cast_w: proj_w fp32 -> bf16 (fallback path when ws has no spare region).
// ---------------------------------------------------------------------------
__global__ __launch_bounds__(256) void cast_w(
    const float* __restrict__ w, unsigned short* __restrict__ wb)
{
  int g = blockIdx.x * 256 + threadIdx.x;
  size_t e = (size_t)g * 8;
  float4 a = *(const float4*)(w + e);
  float4 b = *(const float4*)(w + e + 4);
  ushort4 u0, u1;
  u0.x = f2b(a.x); u0.y = f2b(a.y); u0.z = f2b(a.z); u0.w = f2b(a.w);
  u1.x = f2b(b.x); u1.y = f2b(b.y); u1.z = f2b(b.z); u1.w = f2b(b.w);
  *(ushort4*)(wb + e) = u0;
  *(ushort4*)(wb + e + 4) = u1;
}

// ---------------------------------------------------------------------------
// Attention, round-8/9: one block per (window, HEAD-PAIR); 4-stage pipeline
// {(h0,half0),(h0,half1),(h1,half0),(h1,half1)} over a K/V double buffer.
// KEY FIX vs r7: __syncthreads() emits `s_waitcnt vmcnt(0)` before s_barrier
// (guide §5 barrier-drain) — r7's "prefetch" was drained at every barrier
// and ran synchronously. Now: raw s_barrier + counted vmcnt + explicit
// lgkmcnt(0) (T3+T4), so stage s+1's K-DMA + V-reg loads stay in flight
// across barriers during stage s's compute. Grid 512 = 1 round at
// 2 blocks/CU; prologue latency paid once per block, not per half.
// Epilogue scratch moved from sK (now live) to enlarged sP (stride-72 view).
// Hang-audit (r8 resubmit): 7 uniform s_barriers, no divergent control flow
// around any barrier; every buffer overwrite is post-barrier vs its readers;
// VMCNT(8) accounts stores-in-vmcnt (8 epilogue stores may stay in flight).
// ---------------------------------------------------------------------------
__global__ __launch_bounds__(256, 2) void attn(
    const unsigned short* __restrict__ qkvh,
    unsigned short* __restrict__ ow)
{
  __shared__ __align__(16) unsigned short sK[2][128 * 64];
  __shared__ __align__(16) unsigned short sV[2][64 * 128];
  __shared__ __align__(16) unsigned short sP[4][16 * 72];

  const int t = threadIdx.x;
  const int lane = t & 63, wid = t >> 6;
  const int l15 = lane & 15, quad = lane >> 4;
  const int wwin = blockIdx.x >> 3;
  const int hp = blockIdx.x & 7;
  const int h0 = hp * 2, h1 = hp * 2 + 1;

  const unsigned short* Qb = qkvh;
  const unsigned short* Kb = qkvh + (size_t)16 * (MTOT * HDIM);
  const unsigned short* Vb = qkvh + (size_t)32 * (MTOT * HDIM);

  // K staging: async global_load_lds, linear LDS dest + inverse-swizzled
  // per-lane global source (verified r7). Wave w covers keys [w*32,w*32+32).
  const int l3 = lane >> 3, l7 = lane & 7;
  auto stageK = [&](int buf, int h, int half) {
    const unsigned short* src = Kb + (size_t)h * (MTOT * HDIM) +
        (size_t)(wwin * 256 + half * 128 + wid * 32 + l3) * HDIM +
        (l7 ^ l3) * 8;
#pragma unroll
    for (int p = 0; p < 4; ++p)
      gload16(src + (size_t)(p * 8) * HDIM,
              (char*)&sK[buf][(wid * 32 + p * 8) * 64]);
  };

  // V: reg-staged (transpose scatter); loads issued early, writes later.
  const int vkey = t >> 1, vhx = t & 1;
  auto loadV = [&](int h, int half, bf16x8* vr) {
    const unsigned short* src = Vb + (size_t)h * (MTOT * HDIM) +
        (size_t)(wwin * 256 + half * 128 + vkey) * HDIM + vhx * 32;
#pragma unroll
    for (int c = 0; c < 4; ++c) vr[c] = *(const bf16x8*)(src + c * 8);
  };
  auto writeV = [&](int buf, bf16x8* vr) {
    int kc3 = vkey >> 3, k7 = vkey & 7;
#pragma unroll
    for (int c = 0; c < 4; ++c)
#pragma unroll
      for (int j = 0; j < 8; ++j) {
        int d = vhx * 32 + c * 8 + j;
        sV[buf][d * 128 + ((kc3 ^ (d & 7)) * 8) + k7] =
            (unsigned short)vr[c][j];
      }
  };

  auto loadQ = [&](int h, bf16x8 (&qa)[4][2]) {
#pragma unroll
    for (int qt = 0; qt < 4; ++qt) {
      int i = wwin * 256 + wid * 64 + qt * 16 + l15;
      const unsigned short* qp = Qb + (size_t)h * (MTOT * HDIM) +
                                 (size_t)i * HDIM;
      qa[qt][0] = *(const bf16x8*)(qp + quad * 8);
      qa[qt][1] = *(const bf16x8*)(qp + 32 + quad * 8);
    }
  };

  f32x4 accO[4][4];
  float mrow[4][4], lrow[4][4];
  auto resetAcc = [&]() {
#pragma unroll
    for (int qt = 0; qt < 4; ++qt) {
#pragma unroll
      for (int nt = 0; nt < 4; ++nt) accO[qt][nt] = (f32x4){0.f, 0.f, 0.f, 0.f};
#pragma unroll
      for (int reg = 0; reg < 4; ++reg) { mrow[qt][reg] = -1e30f; lrow[qt][reg] = 0.f; }
    }
  };
  resetAcc();

  auto compute = [&](const unsigned short* sKb, const unsigned short* sVb,
                     const bf16x8 (&qa)[4][2]) {
#pragma unroll
    for (int qt = 0; qt < 4; ++qt) {
      f32x4 accS[8];
#pragma unroll
      for (int nt = 0; nt < 8; ++nt) accS[nt] = (f32x4){0.f, 0.f, 0.f, 0.f};
#pragma unroll
      for (int ks = 0; ks < 2; ++ks) {
#pragma unroll
        for (int nt = 0; nt < 8; ++nt) {
          int key = nt * 16 + l15;
          bf16x8 bk = *(const bf16x8*)(
              sKb + key * 64 + (((ks * 4 + quad) ^ (key & 7)) * 8));
          accS[nt] = __builtin_amdgcn_mfma_f32_16x16x32_bf16(
              qa[qt][ks], bk, accS[nt], 0, 0, 0);
        }
      }
#pragma unroll
      for (int reg = 0; reg < 4; ++reg) {
        float mx = accS[0][reg];
#pragma unroll
        for (int nt = 1; nt < 8; ++nt) mx = fmaxf(mx, accS[nt][reg]);
#pragma unroll
        for (int off = 1; off < 16; off <<= 1)
          mx = fmaxf(mx, __shfl_xor(mx, off, 64));
        float mold = mrow[qt][reg];
        float mnew = fmaxf(mold, mx);
        float alpha = __expf(mold - mnew);
        mrow[qt][reg] = mnew;
        float ls = 0.f;
#pragma unroll
        for (int nt = 0; nt < 8; ++nt) {
          float p = __expf(accS[nt][reg] - mnew);
          accS[nt][reg] = p;
          ls += p;
        }
#pragma unroll
        for (int off = 1; off < 16; off <<= 1) ls += __shfl_xor(ls, off, 64);
        lrow[qt][reg] = lrow[qt][reg] * alpha + ls;
#pragma unroll
        for (int nt = 0; nt < 4; ++nt) accO[qt][nt][reg] *= alpha;
      }
#pragma unroll
      for (int kc = 0; kc < 4; ++kc) {
#pragma unroll
        for (int nt2 = 0; nt2 < 2; ++nt2) {
#pragma unroll
          for (int reg = 0; reg < 4; ++reg) {
            sP[wid][(quad * 4 + reg) * 40 + nt2 * 16 + l15] =
                f2b(accS[kc * 2 + nt2][reg]);
          }
        }
        bf16x8 pa = *(const bf16x8*)(&sP[wid][l15 * 40 + quad * 8]);
#pragma unroll
        for (int nt = 0; nt < 4; ++nt) {
          int d = nt * 16 + l15;
          bf16x8 bv = *(const bf16x8*)(
              sVb + d * 128 + (((kc * 4 + quad) ^ (d & 7)) * 8));
          accO[qt][nt] = __builtin_amdgcn_mfma_f32_16x16x32_bf16(
              pa, bv, accO[qt][nt], 0, 0, 0);
        }
      }
    }
  };

  // vectorized output: per-wave transpose through sP (stride-72 view),
  // 16B/lane stores. Wave-local, program-ordered vs compute's sP use.
  const int rlane = lane >> 3;
  const int clane = (lane & 7) * 8;
  auto epilogue = [&](int h) {
    unsigned short* scr = &sP[wid][0];
#pragma unroll
    for (int qt = 0; qt < 4; ++qt) {
#pragma unroll
      for (int reg = 0; reg < 4; ++reg) {
        float invl = 1.0f / lrow[qt][reg];
        int r = quad * 4 + reg;
#pragma unroll
        for (int nt = 0; nt < 4; ++nt)
          scr[r * 72 + nt * 16 + l15] = f2b(accO[qt][nt][reg] * invl);
      }
#pragma unroll
      for (int rr = 0; rr < 2; ++rr) {
        int row = rr * 8 + rlane;
        bf16x8 vv = *(const bf16x8*)(scr + row * 72 + clane);
        int i = wwin * 256 + wid * 64 + qt * 16 + row;
        *(bf16x8*)(ow + (size_t)i * EMBED + h * HDIM + clane) = vv;
      }
    }
  };

  bf16x8 vr0[4], vr1[4];
  bf16x8 qa0[4][2], qa1[4][2];

  // ---- prologue: stage s0 + issue s1; pay full latency once ----
  stageK(0, h0, 0);            // 4 vm
  loadV(h0, 0, vr0);           // +4
  loadQ(h0, qa0);              // +8
  loadQ(h1, qa1);              // +8
  VMCNT(0);                    // K(s0) in LDS; vr0/qa in regs
  writeV(0, vr0);
  stageK(1, h0, 1);            // s1 K in flight
  loadV(h0, 1, vr1);           // s1 V in flight  (8 outstanding)
  LGKM0();                     // sV[0] writes done
  BARRIER();                   // buf0 published; s1 loads still in flight

  // ---- stage 0: (h0, half0) ----
  compute(&sK[0][0], &sV[0][0], qa0);
  VMCNT(0);                    // s1's K+V arrived
  BARRIER();                   // all waves done reading buf0
  writeV(1, vr1);
  stageK(0, h1, 0);            // s2 in flight
  loadV(h1, 0, vr0);
  LGKM0();
  BARRIER();                   // buf1 published; s2 in flight

  // ---- stage 1: (h0, half1) ----
  compute(&sK[1][0], &sV[1][0], qa0);
  VMCNT(0);                    // s2 arrived
  BARRIER();
  writeV(0, vr0);
  stageK(1, h1, 1);            // s3 in flight (8 vm)
  loadV(h1, 1, vr1);
  epilogue(h0);                // h0 output stores overlap s3's flight
  resetAcc();
  LGKM0();
  BARRIER();                   // buf0 (h1,half0) published; s3 in flight

  // ---- stage 2: (h1, half0) ----
  compute(&sK[0][0], &sV[0][0], qa1);
  VMCNT(8);                    // s3's 8 loads (oldest) done; stores may fly
  BARRIER();
  writeV(1, vr1);
  LGKM0();
  BARRIER();                   // buf1 (h1,half1) published

  // ---- stage 3: (h1, half1) ----
  compute(&sK[1][0], &sV[1][0], qa1);
  epilogue(h1);
}

// ---------------------------------------------------------------------------
extern "C" void kernel_launch(void* const* d_in, const int* in_sizes, int n_in,
                              void* d_out, int out_size, void* d_ws, size_t ws_size,
                              hipStream_t stream) {
  const float* x        = (const float*)d_in[0];
  const float* qkv_w    = (const float*)d_in[1];
  const float* qkv_b    = (const float*)d_in[2];
  const float* proj_w   = (const float*)d_in[3];
  const float* proj_b   = (const float*)d_in[4];
  const float* padding  = (const float*)d_in[5];
  const float* rope_cos = (const float*)d_in[6];
  const float* rope_sin = (const float*)d_in[7];
  const int*   kvi      = (const int*)d_in[8];

  // ws layout:
  //   [0, 100.66M):       qkvh — head-major, window-permuted [48][16384][64]
  //                       bf16; roped in-place by rope_qk.
  //   [100.66M, +33.55M): xb (cast+gemm_qkv) then ow (attn output,
  //                       window-permuted [16384][1024] bf16, gemm_proj A)
  //   [134.22M, +2M):     wpb (proj_w bf16) IF ws_size permits; else wpb
  //                       falls back to the dead Q region + cast_w launch.
  // d_out scratch: head: wqb (6.3 MB); tail: inv (64 KB int32) — both read
  // only by gemm_qkv, which completes before gemm_proj (stream order).
  const size_t QKVH_B = (size_t)MTOT * THREE_EMBED * 2;   // 100,663,296
  const size_t R_B    = (size_t)MTOT * EMBED * 2;         //  33,554,432
  const size_t W_B    = (size_t)EMBED * EMBED * 2;        //   2,097,152
  unsigned short* qkvh = (unsigned short*)d_ws;
  unsigned short* R    = (unsigned short*)((char*)d_ws + QKVH_B);
  unsigned short* xb = R;
  unsigned short* ow = R;
  unsigned short* wqb = (unsigned short*)d_out;
  const bool roomy = ws_size >= QKVH_B + R_B + W_B;
  unsigned short* wpb = roomy
      ? (unsigned short*)((char*)d_ws + QKVH_B + R_B)
      : qkvh;  // Q region, dead after attn (fallback)
  int* inv = (int*)((char*)d_out + (size_t)LTOT * EMBED * 4 - (size_t)MTOT * 4);
  float* out = (float*)d_out;

  cast_inputs<<<4096, 256, 0, stream>>>(
      x, padding, qkv_w, roomy ? proj_w : nullptr, kvi, xb, wqb, wpb, inv,
      roomy ? (EMBED * EMBED / 8) : 0);
  gemm256<0><<<dim3(64, 12), 512, 0, stream>>>(xb, wqb, qkv_b, inv, qkvh,
                                               nullptr);
  rope_qk<<<8192, 256, 0, stream>>>(rope_cos, rope_sin, qkvh);
  attn<<<dim3(64 * 8), 256, 0, stream>>>(qkvh, ow);
  if (!roomy) cast_w<<<512, 256, 0, stream>>>(proj_w, wpb);
  gemm256<1><<<dim3(64, 4), 512, 0, stream>>>(ow, wpb, proj_b, kvi, nullptr,
                                              out);
}